// Round 3
// baseline (157.583 us; speedup 1.0000x reference)
//
#include <hip/hip_runtime.h>

#define NBK 10
#define KK  9

constexpr int Bv  = 4;
constexpr int Vv  = 5023;
constexpr int TOT = Bv * Vv;   // 20092
constexpr int UXP = 12;        // padded ux row stride (float4-friendly)

// ---------------------------------------------------------------------------
// Encoder: h0 = relu(x @ Win), ux0 = h0 @ u0.  One thread per vertex.
// ---------------------------------------------------------------------------
__global__ __launch_bounds__(256) void encoder_kernel(
    const float* __restrict__ x,     // [TOT,3]
    const float* __restrict__ Win,   // [3,16]
    const float* __restrict__ u0,    // [16,9]
    float* __restrict__ h,           // [TOT,16]
    float* __restrict__ ux)          // [TOT,UXP]
{
    int vv = blockIdx.x * 256 + threadIdx.x;
    if (vv >= TOT) return;
    float x0 = x[vv * 3 + 0], x1 = x[vv * 3 + 1], x2 = x[vv * 3 + 2];
    float hv[16];
#pragma unroll
    for (int c = 0; c < 16; c++) {
        float s = x0 * Win[c] + x1 * Win[16 + c] + x2 * Win[32 + c];
        hv[c] = fmaxf(s, 0.0f);
    }
    float4* hw = reinterpret_cast<float4*>(&h[(size_t)vv * 16]);
#pragma unroll
    for (int j = 0; j < 4; j++)
        hw[j] = make_float4(hv[4 * j], hv[4 * j + 1], hv[4 * j + 2], hv[4 * j + 3]);
#pragma unroll
    for (int k = 0; k < KK; k++) {
        float s = 0.0f;
#pragma unroll
        for (int c = 0; c < 16; c++) s = fmaf(hv[c], u0[c * KK + k], s);
        ux[(size_t)vv * UXP + k] = s;
    }
}

// ---------------------------------------------------------------------------
// Merge-tree reduce over a 16-lane group: on entry a[0..15] are per-lane
// partials of 16 outputs; on exit returns out[t] (sum over the 16 lanes).
// 15 shuffles instead of 64; all register indices compile-time constant.
// ---------------------------------------------------------------------------
__device__ __forceinline__ float merge16(float* a, int t)
{
#pragma unroll
    for (int j = 0; j < 8; j++) {
        float send = (t & 8) ? a[j] : a[j + 8];
        float keep = (t & 8) ? a[j + 8] : a[j];
        a[j] = keep + __shfl_xor(send, 8, 16);
    }
#pragma unroll
    for (int j = 0; j < 4; j++) {
        float send = (t & 4) ? a[j] : a[j + 4];
        float keep = (t & 4) ? a[j + 4] : a[j];
        a[j] = keep + __shfl_xor(send, 4, 16);
    }
#pragma unroll
    for (int j = 0; j < 2; j++) {
        float send = (t & 2) ? a[j] : a[j + 2];
        float keep = (t & 2) ? a[j + 2] : a[j];
        a[j] = keep + __shfl_xor(send, 2, 16);
    }
    {
        float send = (t & 1) ? a[0] : a[1];
        float keep = (t & 1) ? a[1] : a[0];
        a[0] = keep + __shfl_xor(send, 1, 16);
    }
    return a[0];
}

// ---------------------------------------------------------------------------
// NLayer: 16 lanes per vertex, 16 vertices per 256-thread block.
// ZERO LDS, ZERO barriers: all exchange via wave-local shuffles; W and u
// read directly from global (L1-resident, float4-contiguous in Cout).
// Lane t owns input channel t (and t+16 when CIN==32) and output channel t
// (and t+16 when COUT==32).
// ---------------------------------------------------------------------------
template<int CIN, int COUT, bool LAST>
__global__ __launch_bounds__(256) void nlayer_kernel(
    const float* __restrict__ hin,   // [TOT,CIN]
    const float* __restrict__ uxin,  // [TOT,UXP]
    const int*   __restrict__ adj,   // [Vv,NBK]
    const float* __restrict__ W,     // [CIN,KK,COUT]
    const float* __restrict__ bvec,  // [COUT]
    const float* __restrict__ cvec,  // [KK]
    const float* __restrict__ unx,   // [COUT,KK] (or Wout [3,3] if LAST)
    float* __restrict__ hout,        // [TOT,COUT]
    float* __restrict__ uxout,       // [TOT,UXP]
    float* __restrict__ dout)        // [TOT,3] if LAST
{
    const int tid = threadIdx.x;
    const int g = tid >> 4;
    const int t = tid & 15;
    const int vv = blockIdx.x * 16 + g;
    if (vv >= TOT) return;            // whole 16-lane group exits; no barriers
    const int b = vv / Vv;
    const int v = vv - b * Vv;

    // --- adjacency row (L1-broadcast across the group's 16 lanes) ---
    int nb[NBK];
    const int2* arow = reinterpret_cast<const int2*>(&adj[v * NBK]);
#pragma unroll
    for (int j = 0; j < 5; j++) { int2 p = arow[j]; nb[2 * j] = p.x; nb[2 * j + 1] = p.y; }

    // --- gather neighbor features for owned channel(s); issue early ---
    float hn0[NBK], hn1[NBK];
#pragma unroll
    for (int n = 0; n < NBK; n++) {
        const int a = nb[n];
        const float* hb = &hin[((size_t)b * Vv + (a - 1)) * CIN];
        hn0[n] = a ? hb[t] : 0.0f;
        if constexpr (CIN == 32) hn1[n] = a ? hb[t + 16] : 0.0f;
    }

    int cnt = 0;
#pragma unroll
    for (int n = 0; n < NBK; n++) cnt += (nb[n] != 0) ? 1 : 0;
    const float rec = cnt ? (1.0f / (float)cnt) : 0.0f;

    // --- softmax over k: lane t<10 handles neighbor t, fully in registers ---
    float q[KK] = {};
    if (t < NBK) {
        const float* su = &uxin[(size_t)vv * UXP];
        const float4 s0 = *reinterpret_cast<const float4*>(su);
        const float4 s1 = *reinterpret_cast<const float4*>(su + 4);
        const float  s8 = su[8];
        const int a = nb[t];
        float4 n0 = make_float4(0.f, 0.f, 0.f, 0.f), n1 = n0;
        float  n8 = 0.0f;
        if (a) {
            const float* nu = &uxin[((size_t)b * Vv + (a - 1)) * UXP];
            n0 = *reinterpret_cast<const float4*>(nu);
            n1 = *reinterpret_cast<const float4*>(nu + 4);
            n8 = nu[8];
        }
        float lg[KK] = { s0.x + n0.x + cvec[0], s0.y + n0.y + cvec[1],
                         s0.z + n0.z + cvec[2], s0.w + n0.w + cvec[3],
                         s1.x + n1.x + cvec[4], s1.y + n1.y + cvec[5],
                         s1.z + n1.z + cvec[6], s1.w + n1.w + cvec[7],
                         s8 + n8 + cvec[8] };
        float m = lg[0];
#pragma unroll
        for (int k = 1; k < KK; k++) m = fmaxf(m, lg[k]);
        float sum = 0.0f;
#pragma unroll
        for (int k = 0; k < KK; k++) { q[k] = __expf(lg[k] - m); sum += q[k]; }
        const float r = 1.0f / sum;
#pragma unroll
        for (int k = 0; k < KK; k++) q[k] *= r;
    }

    // --- G-phase: g[k] = sum_n q[n][k] * h_nb[n][c_own]; q via shuffles ---
    float g0[KK], g1[KK];
#pragma unroll
    for (int k = 0; k < KK; k++) { g0[k] = 0.0f; g1[k] = 0.0f; }
#pragma unroll
    for (int n = 0; n < NBK; n++) {
#pragma unroll
        for (int k = 0; k < KK; k++) {
            const float qnk = __shfl(q[k], n, 16);
            g0[k] = fmaf(qnk, hn0[n], g0[k]);
            if constexpr (CIN == 32) g1[k] = fmaf(qnk, hn1[n], g1[k]);
        }
    }

    // --- E-phase: acc[o] += g[k] * W[c_own][k][o]; W straight from L1 ---
    if constexpr (!LAST) {
        float acc[COUT] = {};
#pragma unroll
        for (int k = 0; k < KK; k++) {
            const float4* wr = reinterpret_cast<const float4*>(&W[((size_t)t * KK + k) * COUT]);
#pragma unroll
            for (int o4 = 0; o4 < COUT / 4; o4++) {
                const float4 w = wr[o4];
                acc[4 * o4 + 0] = fmaf(g0[k], w.x, acc[4 * o4 + 0]);
                acc[4 * o4 + 1] = fmaf(g0[k], w.y, acc[4 * o4 + 1]);
                acc[4 * o4 + 2] = fmaf(g0[k], w.z, acc[4 * o4 + 2]);
                acc[4 * o4 + 3] = fmaf(g0[k], w.w, acc[4 * o4 + 3]);
            }
            if constexpr (CIN == 32) {
                const float4* wr2 = reinterpret_cast<const float4*>(&W[((size_t)(t + 16) * KK + k) * COUT]);
#pragma unroll
                for (int o4 = 0; o4 < COUT / 4; o4++) {
                    const float4 w = wr2[o4];
                    acc[4 * o4 + 0] = fmaf(g1[k], w.x, acc[4 * o4 + 0]);
                    acc[4 * o4 + 1] = fmaf(g1[k], w.y, acc[4 * o4 + 1]);
                    acc[4 * o4 + 2] = fmaf(g1[k], w.z, acc[4 * o4 + 2]);
                    acc[4 * o4 + 3] = fmaf(g1[k], w.w, acc[4 * o4 + 3]);
                }
            }
        }

        // merge-tree reduce: lane t ends with out[t] (and out[t+16])
        float o0 = merge16(acc, t);
        float h0v = fmaxf(fmaf(o0, rec, bvec[t]), 0.0f);
        hout[(size_t)vv * COUT + t] = h0v;
        float h1v = 0.0f;
        if constexpr (COUT == 32) {
            float o1 = merge16(acc + 16, t);
            h1v = fmaxf(fmaf(o1, rec, bvec[t + 16]), 0.0f);
            hout[(size_t)vv * COUT + 16 + t] = h1v;
        }

        // fused ux for next layer: lane t<9 accumulates ux[t]
        float uxv = 0.0f;
#pragma unroll
        for (int o = 0; o < 16; o++) {
            const float hb = __shfl(h0v, o, 16);
            if (t < KK) uxv = fmaf(hb, unx[o * KK + t], uxv);
        }
        if constexpr (COUT == 32) {
#pragma unroll
            for (int o = 0; o < 16; o++) {
                const float hb = __shfl(h1v, o, 16);
                if (t < KK) uxv = fmaf(hb, unx[(o + 16) * KK + t], uxv);
            }
        }
        if (t < KK) uxout[(size_t)vv * UXP + t] = uxv;
    } else {
        // COUT == 3, fused decoder
        float acc[3] = {};
#pragma unroll
        for (int k = 0; k < KK; k++) {
            const float* wr = &W[((size_t)t * KK + k) * 3];
            acc[0] = fmaf(g0[k], wr[0], acc[0]);
            acc[1] = fmaf(g0[k], wr[1], acc[1]);
            acc[2] = fmaf(g0[k], wr[2], acc[2]);
        }
#pragma unroll
        for (int o = 0; o < 3; o++) {
            acc[o] += __shfl_xor(acc[o], 1, 16);
            acc[o] += __shfl_xor(acc[o], 2, 16);
            acc[o] += __shfl_xor(acc[o], 4, 16);
            acc[o] += __shfl_xor(acc[o], 8, 16);
        }
        float hnew[3];
#pragma unroll
        for (int o = 0; o < 3; o++)
            hnew[o] = fmaxf(fmaf(acc[o], rec, bvec[o]), 0.0f);
        if (t < 3) {
            float s = 0.0f;
#pragma unroll
            for (int j = 0; j < 3; j++)
                s = fmaf(hnew[j], unx[j * 3 + t], s);
            dout[(size_t)vv * 3 + t] = s;
        }
    }
}

// ---------------------------------------------------------------------------
extern "C" void kernel_launch(void* const* d_in, const int* in_sizes, int n_in,
                              void* d_out, int out_size, void* d_ws, size_t ws_size,
                              hipStream_t stream)
{
    const float* x    = (const float*)d_in[0];
    const int*   adj  = (const int*)  d_in[1];
    const float* Win  = (const float*)d_in[2];
    const float* Wout = (const float*)d_in[3];
    const float *W[6], *bb[6], *uu[6], *cc[6];
    for (int i = 0; i < 6; i++) {
        W[i]  = (const float*)d_in[4 + 4 * i];
        bb[i] = (const float*)d_in[5 + 4 * i];
        uu[i] = (const float*)d_in[6 + 4 * i];
        cc[i] = (const float*)d_in[7 + 4 * i];
    }
    float* out = (float*)d_out;

    // Workspace: hA [TOT*16], hB [TOT*32], uxA/uxB [TOT*UXP]
    float* hA  = (float*)d_ws;
    float* hB  = hA  + (size_t)TOT * 16;
    float* uxA = hB  + (size_t)TOT * 32;
    float* uxB = uxA + (size_t)TOT * UXP;

    int nbv = (TOT + 255) / 256;
    encoder_kernel<<<nbv, 256, 0, stream>>>(x, Win, uu[0], hA, uxA);

    int nb = (TOT + 15) / 16;
    nlayer_kernel<16, 16, false><<<nb, 256, 0, stream>>>(hA, uxA, adj, W[0], bb[0], cc[0], uu[1], hB, uxB, nullptr);
    nlayer_kernel<16, 16, false><<<nb, 256, 0, stream>>>(hB, uxB, adj, W[1], bb[1], cc[1], uu[2], hA, uxA, nullptr);
    nlayer_kernel<16, 32, false><<<nb, 256, 0, stream>>>(hA, uxA, adj, W[2], bb[2], cc[2], uu[3], hB, uxB, nullptr);
    nlayer_kernel<32, 16, false><<<nb, 256, 0, stream>>>(hB, uxB, adj, W[3], bb[3], cc[3], uu[4], hA, uxA, nullptr);
    nlayer_kernel<16, 16, false><<<nb, 256, 0, stream>>>(hA, uxA, adj, W[4], bb[4], cc[4], uu[5], hB, uxB, nullptr);
    nlayer_kernel<16, 3, true ><<<nb, 256, 0, stream>>>(hB, uxB, adj, W[5], bb[5], cc[5], Wout, nullptr, nullptr, out);
}

// Round 4
// 145.050 us; speedup vs baseline: 1.0864x; 1.0864x over previous
//
#include <hip/hip_runtime.h>

#define NBK 10
#define KK  9
#define SC_AGENT __HIP_MEMORY_SCOPE_AGENT

constexpr int Bv  = 4;
constexpr int Vv  = 5023;
constexpr int TOT = Bv * Vv;   // 20092
constexpr int UXP = 12;        // padded ux row stride
constexpr int NBLK_F = 628;    // fused grid: block owns groups 2*bid, 2*bid+1
constexpr int NBARS  = 6;

// ---------------------------------------------------------------------------
// Device-wide barrier state: 16 split arrival counters (128B apart) + 2-level
// combine + release flag. One Bar per barrier instance (monotone, no reuse).
// ---------------------------------------------------------------------------
struct Bar {
    int lo[16 * 32];
    int hi;   int pad1[31];
    int flag; int pad2[31];
};

__device__ __forceinline__ void barrier_sync(Bar* bar, int bid, int tid)
{
    __syncthreads();   // drains each wave's vmem (stores in L2) before arrival
    if (tid == 0) {
        const int g    = bid & 15;
        const int need = (NBLK_F >> 4) + ((g < (NBLK_F & 15)) ? 1 : 0);
        // release RMW: writes back this XCD's L2 so all prior stores reach L3
        const int old = __hip_atomic_fetch_add(&bar->lo[g * 32], 1,
                                               __ATOMIC_ACQ_REL, SC_AGENT);
        if (old == need - 1) {
            const int oh = __hip_atomic_fetch_add(&bar->hi, 1,
                                                  __ATOMIC_ACQ_REL, SC_AGENT);
            if (oh == 15)
                __hip_atomic_store(&bar->flag, 1, __ATOMIC_RELEASE, SC_AGENT);
        }
        while (__hip_atomic_load(&bar->flag, __ATOMIC_RELAXED, SC_AGENT) == 0)
            __builtin_amdgcn_s_sleep(4);
        // acquire: invalidate stale L2 lines before reading producers' data
        (void)__hip_atomic_load(&bar->flag, __ATOMIC_ACQUIRE, SC_AGENT);
    }
    __syncthreads();
}

// ---------------------------------------------------------------------------
// 16-lane merge-tree reduce: entry a[0..15] = per-lane partials of 16 outputs;
// exit: returns out[t] (sum over the 16 lanes). 15 shuffles.
// ---------------------------------------------------------------------------
__device__ __forceinline__ float merge16(float* a, int t)
{
#pragma unroll
    for (int j = 0; j < 8; j++) {
        float send = (t & 8) ? a[j] : a[j + 8];
        float keep = (t & 8) ? a[j + 8] : a[j];
        a[j] = keep + __shfl_xor(send, 8, 16);
    }
#pragma unroll
    for (int j = 0; j < 4; j++) {
        float send = (t & 4) ? a[j] : a[j + 4];
        float keep = (t & 4) ? a[j + 4] : a[j];
        a[j] = keep + __shfl_xor(send, 4, 16);
    }
#pragma unroll
    for (int j = 0; j < 2; j++) {
        float send = (t & 2) ? a[j] : a[j + 2];
        float keep = (t & 2) ? a[j + 2] : a[j];
        a[j] = keep + __shfl_xor(send, 2, 16);
    }
    {
        float send = (t & 1) ? a[0] : a[1];
        float keep = (t & 1) ? a[1] : a[0];
        a[0] = keep + __shfl_xor(send, 1, 16);
    }
    return a[0];
}

// ---------------------------------------------------------------------------
// One NLayer step (verified round-3 math). act-predicated; no early returns.
// ---------------------------------------------------------------------------
template<int CIN, int COUT, bool LAST>
__device__ __forceinline__ void nlayer_step(
    bool act, int b, int vv, int t, const int* nb, float rec,
    const float* __restrict__ hin, const float* __restrict__ uxin,
    const float* __restrict__ W, const float* __restrict__ bvec,
    const float* __restrict__ cvec, const float* __restrict__ unx,
    float* __restrict__ hout, float* __restrict__ uxout, float* __restrict__ dout)
{
    // gather neighbor features for owned channel(s)
    float hn0[NBK], hn1[NBK];
#pragma unroll
    for (int n = 0; n < NBK; n++) {
        const int a = nb[n];
        const float* hb = &hin[((size_t)b * Vv + (a - 1)) * CIN];
        hn0[n] = a ? hb[t] : 0.0f;
        if constexpr (CIN == 32) hn1[n] = a ? hb[t + 16] : 0.0f;
        else                     hn1[n] = 0.0f;
    }

    // softmax over k: lane t<10 handles neighbor t, fully in registers
    float q[KK] = {};
    if (act && t < NBK) {
        const float* su = &uxin[(size_t)vv * UXP];
        const float4 s0 = *reinterpret_cast<const float4*>(su);
        const float4 s1 = *reinterpret_cast<const float4*>(su + 4);
        const float  s8 = su[8];
        const int a = nb[t];
        float4 n0 = make_float4(0.f, 0.f, 0.f, 0.f), n1 = n0;
        float  n8 = 0.0f;
        if (a) {
            const float* nu = &uxin[((size_t)b * Vv + (a - 1)) * UXP];
            n0 = *reinterpret_cast<const float4*>(nu);
            n1 = *reinterpret_cast<const float4*>(nu + 4);
            n8 = nu[8];
        }
        float lg[KK] = { s0.x + n0.x + cvec[0], s0.y + n0.y + cvec[1],
                         s0.z + n0.z + cvec[2], s0.w + n0.w + cvec[3],
                         s1.x + n1.x + cvec[4], s1.y + n1.y + cvec[5],
                         s1.z + n1.z + cvec[6], s1.w + n1.w + cvec[7],
                         s8 + n8 + cvec[8] };
        float m = lg[0];
#pragma unroll
        for (int k = 1; k < KK; k++) m = fmaxf(m, lg[k]);
        float sum = 0.0f;
#pragma unroll
        for (int k = 0; k < KK; k++) { q[k] = __expf(lg[k] - m); sum += q[k]; }
        const float r = 1.0f / sum;
#pragma unroll
        for (int k = 0; k < KK; k++) q[k] *= r;
    }

    // G-phase: g[k] = sum_n q[n][k] * h_nb[n][c_own]
    float g0[KK], g1[KK];
#pragma unroll
    for (int k = 0; k < KK; k++) { g0[k] = 0.0f; g1[k] = 0.0f; }
#pragma unroll
    for (int n = 0; n < NBK; n++) {
#pragma unroll
        for (int k = 0; k < KK; k++) {
            const float qnk = __shfl(q[k], n, 16);
            g0[k] = fmaf(qnk, hn0[n], g0[k]);
            if constexpr (CIN == 32) g1[k] = fmaf(qnk, hn1[n], g1[k]);
        }
    }

    if constexpr (!LAST) {
        float acc[COUT] = {};
#pragma unroll
        for (int k = 0; k < KK; k++) {
            const float4* wr = reinterpret_cast<const float4*>(&W[((size_t)t * KK + k) * COUT]);
#pragma unroll
            for (int o4 = 0; o4 < COUT / 4; o4++) {
                const float4 w = wr[o4];
                acc[4 * o4 + 0] = fmaf(g0[k], w.x, acc[4 * o4 + 0]);
                acc[4 * o4 + 1] = fmaf(g0[k], w.y, acc[4 * o4 + 1]);
                acc[4 * o4 + 2] = fmaf(g0[k], w.z, acc[4 * o4 + 2]);
                acc[4 * o4 + 3] = fmaf(g0[k], w.w, acc[4 * o4 + 3]);
            }
            if constexpr (CIN == 32) {
                const float4* wr2 = reinterpret_cast<const float4*>(&W[((size_t)(t + 16) * KK + k) * COUT]);
#pragma unroll
                for (int o4 = 0; o4 < COUT / 4; o4++) {
                    const float4 w = wr2[o4];
                    acc[4 * o4 + 0] = fmaf(g1[k], w.x, acc[4 * o4 + 0]);
                    acc[4 * o4 + 1] = fmaf(g1[k], w.y, acc[4 * o4 + 1]);
                    acc[4 * o4 + 2] = fmaf(g1[k], w.z, acc[4 * o4 + 2]);
                    acc[4 * o4 + 3] = fmaf(g1[k], w.w, acc[4 * o4 + 3]);
                }
            }
        }

        float o0 = merge16(acc, t);
        float h0v = fmaxf(fmaf(o0, rec, bvec[t]), 0.0f);
        float h1v = 0.0f;
        if (act) hout[(size_t)vv * COUT + t] = h0v;
        if constexpr (COUT == 32) {
            float o1 = merge16(acc + 16, t);
            h1v = fmaxf(fmaf(o1, rec, bvec[t + 16]), 0.0f);
            if (act) hout[(size_t)vv * COUT + 16 + t] = h1v;
        }

        // fused ux for next layer
        float uxv = 0.0f;
#pragma unroll
        for (int o = 0; o < 16; o++) {
            const float hb = __shfl(h0v, o, 16);
            if (t < KK) uxv = fmaf(hb, unx[o * KK + t], uxv);
        }
        if constexpr (COUT == 32) {
#pragma unroll
            for (int o = 0; o < 16; o++) {
                const float hb = __shfl(h1v, o, 16);
                if (t < KK) uxv = fmaf(hb, unx[(o + 16) * KK + t], uxv);
            }
        }
        if (act && t < KK) uxout[(size_t)vv * UXP + t] = uxv;
    } else {
        float acc[3] = {};
#pragma unroll
        for (int k = 0; k < KK; k++) {
            const float* wr = &W[((size_t)t * KK + k) * 3];
            acc[0] = fmaf(g0[k], wr[0], acc[0]);
            acc[1] = fmaf(g0[k], wr[1], acc[1]);
            acc[2] = fmaf(g0[k], wr[2], acc[2]);
        }
#pragma unroll
        for (int o = 0; o < 3; o++) {
            acc[o] += __shfl_xor(acc[o], 1, 16);
            acc[o] += __shfl_xor(acc[o], 2, 16);
            acc[o] += __shfl_xor(acc[o], 4, 16);
            acc[o] += __shfl_xor(acc[o], 8, 16);
        }
        float hnew[3];
#pragma unroll
        for (int o = 0; o < 3; o++)
            hnew[o] = fmaxf(fmaf(acc[o], rec, bvec[o]), 0.0f);
        if (act && t < 3) {
            float s = 0.0f;
#pragma unroll
            for (int j = 0; j < 3; j++)
                s = fmaf(hnew[j], unx[j * 3 + t], s);
            dout[(size_t)vv * 3 + t] = s;
        }
    }
}

// ---------------------------------------------------------------------------
struct KArgs {
    const float* x; const int* adj; const float* Win; const float* Wout;
    const float* W[6]; const float* bv[6]; const float* uv[6]; const float* cv[6];
    Bar* bars;
    float* hb[6];   // stage outputs: enc, L0..L4
    float* uxb[6];
    float* out;
};

__global__ __launch_bounds__(256, 3) void fused_kernel(KArgs A)
{
    const int tid = threadIdx.x;
    const int bid = blockIdx.x;

    // ---- encoder: one thread per vertex ----
    {
        const int idx = bid * 256 + tid;
        if (idx < TOT) {
            const float x0 = A.x[idx * 3 + 0], x1 = A.x[idx * 3 + 1], x2 = A.x[idx * 3 + 2];
            float hv[16];
#pragma unroll
            for (int c = 0; c < 16; c++) {
                float s = x0 * A.Win[c] + x1 * A.Win[16 + c] + x2 * A.Win[32 + c];
                hv[c] = fmaxf(s, 0.0f);
            }
            float4* hw = reinterpret_cast<float4*>(&A.hb[0][(size_t)idx * 16]);
#pragma unroll
            for (int j = 0; j < 4; j++)
                hw[j] = make_float4(hv[4 * j], hv[4 * j + 1], hv[4 * j + 2], hv[4 * j + 3]);
#pragma unroll
            for (int k = 0; k < KK; k++) {
                float s = 0.0f;
#pragma unroll
                for (int c = 0; c < 16; c++) s = fmaf(hv[c], A.uv[0][c * KK + k], s);
                A.uxb[0][(size_t)idx * UXP + k] = s;
            }
        }
    }

    // ---- per-group state (adj row / recip loaded ONCE, reused all layers) ----
    const int g = tid >> 4;
    const int t = tid & 15;
    int   nbA[2][NBK];
    float recA[2];
    int   bA[2], vvA[2];
    bool  actA[2];
#pragma unroll
    for (int it = 0; it < 2; ++it) {
        const int grp = bid * 2 + it;
        const int vv  = grp * 16 + g;
        vvA[it]  = vv;
        actA[it] = (vv < TOT);
        int b = 0, v = 0;
        if (actA[it]) { b = vv / Vv; v = vv - b * Vv; }
        bA[it] = b;
        if (actA[it]) {
            const int2* arow = reinterpret_cast<const int2*>(&A.adj[v * NBK]);
#pragma unroll
            for (int j = 0; j < 5; j++) {
                int2 p = arow[j];
                nbA[it][2 * j] = p.x; nbA[it][2 * j + 1] = p.y;
            }
        } else {
#pragma unroll
            for (int n = 0; n < NBK; n++) nbA[it][n] = 0;
        }
        int cnt = 0;
#pragma unroll
        for (int n = 0; n < NBK; n++) cnt += (nbA[it][n] != 0) ? 1 : 0;
        recA[it] = cnt ? (1.0f / (float)cnt) : 0.0f;
    }

    barrier_sync(&A.bars[0], bid, tid);
#pragma unroll
    for (int it = 0; it < 2; ++it)
        nlayer_step<16, 16, false>(actA[it], bA[it], vvA[it], t, nbA[it], recA[it],
            A.hb[0], A.uxb[0], A.W[0], A.bv[0], A.cv[0], A.uv[1], A.hb[1], A.uxb[1], nullptr);
    barrier_sync(&A.bars[1], bid, tid);
#pragma unroll
    for (int it = 0; it < 2; ++it)
        nlayer_step<16, 16, false>(actA[it], bA[it], vvA[it], t, nbA[it], recA[it],
            A.hb[1], A.uxb[1], A.W[1], A.bv[1], A.cv[1], A.uv[2], A.hb[2], A.uxb[2], nullptr);
    barrier_sync(&A.bars[2], bid, tid);
#pragma unroll
    for (int it = 0; it < 2; ++it)
        nlayer_step<16, 32, false>(actA[it], bA[it], vvA[it], t, nbA[it], recA[it],
            A.hb[2], A.uxb[2], A.W[2], A.bv[2], A.cv[2], A.uv[3], A.hb[3], A.uxb[3], nullptr);
    barrier_sync(&A.bars[3], bid, tid);
#pragma unroll
    for (int it = 0; it < 2; ++it)
        nlayer_step<32, 16, false>(actA[it], bA[it], vvA[it], t, nbA[it], recA[it],
            A.hb[3], A.uxb[3], A.W[3], A.bv[3], A.cv[3], A.uv[4], A.hb[4], A.uxb[4], nullptr);
    barrier_sync(&A.bars[4], bid, tid);
#pragma unroll
    for (int it = 0; it < 2; ++it)
        nlayer_step<16, 16, false>(actA[it], bA[it], vvA[it], t, nbA[it], recA[it],
            A.hb[4], A.uxb[4], A.W[4], A.bv[4], A.cv[4], A.uv[5], A.hb[5], A.uxb[5], nullptr);
    barrier_sync(&A.bars[5], bid, tid);
#pragma unroll
    for (int it = 0; it < 2; ++it)
        nlayer_step<16, 3, true >(actA[it], bA[it], vvA[it], t, nbA[it], recA[it],
            A.hb[5], A.uxb[5], A.W[5], A.bv[5], A.cv[5], A.Wout, nullptr, nullptr, A.out);
}

// ===========================================================================
// Fallback: verified round-3 seven-kernel path.
// ===========================================================================
__global__ __launch_bounds__(256) void encoder_kernel(
    const float* __restrict__ x, const float* __restrict__ Win,
    const float* __restrict__ u0, float* __restrict__ h, float* __restrict__ ux)
{
    int vv = blockIdx.x * 256 + threadIdx.x;
    if (vv >= TOT) return;
    float x0 = x[vv * 3 + 0], x1 = x[vv * 3 + 1], x2 = x[vv * 3 + 2];
    float hv[16];
#pragma unroll
    for (int c = 0; c < 16; c++) {
        float s = x0 * Win[c] + x1 * Win[16 + c] + x2 * Win[32 + c];
        hv[c] = fmaxf(s, 0.0f);
    }
    float4* hw = reinterpret_cast<float4*>(&h[(size_t)vv * 16]);
#pragma unroll
    for (int j = 0; j < 4; j++)
        hw[j] = make_float4(hv[4 * j], hv[4 * j + 1], hv[4 * j + 2], hv[4 * j + 3]);
#pragma unroll
    for (int k = 0; k < KK; k++) {
        float s = 0.0f;
#pragma unroll
        for (int c = 0; c < 16; c++) s = fmaf(hv[c], u0[c * KK + k], s);
        ux[(size_t)vv * UXP + k] = s;
    }
}

template<int CIN, int COUT, bool LAST>
__global__ __launch_bounds__(256) void nlayer_kernel(
    const float* __restrict__ hin, const float* __restrict__ uxin,
    const int* __restrict__ adj, const float* __restrict__ W,
    const float* __restrict__ bvec, const float* __restrict__ cvec,
    const float* __restrict__ unx, float* __restrict__ hout,
    float* __restrict__ uxout, float* __restrict__ dout)
{
    const int tid = threadIdx.x;
    const int g = tid >> 4;
    const int t = tid & 15;
    const int vv = blockIdx.x * 16 + g;
    if (vv >= TOT) return;
    const int b = vv / Vv;
    const int v = vv - b * Vv;
    int nb[NBK];
    const int2* arow = reinterpret_cast<const int2*>(&adj[v * NBK]);
#pragma unroll
    for (int j = 0; j < 5; j++) { int2 p = arow[j]; nb[2 * j] = p.x; nb[2 * j + 1] = p.y; }
    int cnt = 0;
#pragma unroll
    for (int n = 0; n < NBK; n++) cnt += (nb[n] != 0) ? 1 : 0;
    const float rec = cnt ? (1.0f / (float)cnt) : 0.0f;
    nlayer_step<CIN, COUT, LAST>(true, b, vv, t, nb, rec,
        hin, uxin, W, bvec, cvec, unx, hout, uxout, dout);
}

// ---------------------------------------------------------------------------
extern "C" void kernel_launch(void* const* d_in, const int* in_sizes, int n_in,
                              void* d_out, int out_size, void* d_ws, size_t ws_size,
                              hipStream_t stream)
{
    const float* x    = (const float*)d_in[0];
    const int*   adj  = (const int*)  d_in[1];
    const float* Win  = (const float*)d_in[2];
    const float* Wout = (const float*)d_in[3];
    const float *W[6], *bb[6], *uu[6], *cc[6];
    for (int i = 0; i < 6; i++) {
        W[i]  = (const float*)d_in[4 + 4 * i];
        bb[i] = (const float*)d_in[5 + 4 * i];
        uu[i] = (const float*)d_in[6 + 4 * i];
        cc[i] = (const float*)d_in[7 + 4 * i];
    }
    float* out = (float*)d_out;

    // Workspace: [Bar x6 | hb[0..5] | uxb[0..5]]  (no buffer reuse)
    char*  wsb  = (char*)d_ws;
    Bar*   bars = (Bar*)wsb;
    float* p    = (float*)(wsb + 16384);
    const int hsz[6] = {16, 16, 16, 32, 16, 16};
    float* hb[6];  float* uxb[6];
    for (int i = 0; i < 6; i++) { hb[i]  = p; p += (size_t)TOT * hsz[i]; }
    for (int i = 0; i < 6; i++) { uxb[i] = p; p += (size_t)TOT * UXP; }

    // co-residency check (host-side queries; capture-safe)
    int dev = 0, ncu = 0, maxb = 0;
    (void)hipGetDevice(&dev);
    (void)hipDeviceGetAttribute(&ncu, hipDeviceAttributeMultiprocessorCount, dev);
    hipError_t oe = hipOccupancyMaxActiveBlocksPerMultiprocessor(&maxb, fused_kernel, 256, 0);
    const bool use_fused = (oe == hipSuccess) && (ncu > 0) &&
                           ((long)maxb * ncu >= NBLK_F);

    if (use_fused) {
        (void)hipMemsetAsync(d_ws, 0, sizeof(Bar) * NBARS, stream);
        KArgs A;
        A.x = x; A.adj = adj; A.Win = Win; A.Wout = Wout;
        for (int i = 0; i < 6; i++) { A.W[i] = W[i]; A.bv[i] = bb[i]; A.uv[i] = uu[i]; A.cv[i] = cc[i]; }
        A.bars = bars;
        for (int i = 0; i < 6; i++) { A.hb[i] = hb[i]; A.uxb[i] = uxb[i]; }
        A.out = out;
        fused_kernel<<<NBLK_F, 256, 0, stream>>>(A);
        return;
    }

    // fallback: 7-kernel path
    int nbv = (TOT + 255) / 256;
    encoder_kernel<<<nbv, 256, 0, stream>>>(x, Win, uu[0], hb[0], uxb[0]);
    int nb = (TOT + 15) / 16;
    nlayer_kernel<16, 16, false><<<nb, 256, 0, stream>>>(hb[0], uxb[0], adj, W[0], bb[0], cc[0], uu[1], hb[1], uxb[1], nullptr);
    nlayer_kernel<16, 16, false><<<nb, 256, 0, stream>>>(hb[1], uxb[1], adj, W[1], bb[1], cc[1], uu[2], hb[2], uxb[2], nullptr);
    nlayer_kernel<16, 32, false><<<nb, 256, 0, stream>>>(hb[2], uxb[2], adj, W[2], bb[2], cc[2], uu[3], hb[3], uxb[3], nullptr);
    nlayer_kernel<32, 16, false><<<nb, 256, 0, stream>>>(hb[3], uxb[3], adj, W[3], bb[3], cc[3], uu[4], hb[4], uxb[4], nullptr);
    nlayer_kernel<16, 16, false><<<nb, 256, 0, stream>>>(hb[4], uxb[4], adj, W[4], bb[4], cc[4], uu[5], hb[5], uxb[5], nullptr);
    nlayer_kernel<16, 3, true ><<<nb, 256, 0, stream>>>(hb[5], uxb[5], adj, W[5], bb[5], cc[5], Wout, nullptr, nullptr, out);
}